// Round 1
// baseline (1604.417 us; speedup 1.0000x reference)
//
#include <hip/hip_runtime.h>
#include <stdint.h>

// Problem constants
#define B_   16
#define S_   1024
#define D_   512
#define H_   8
#define DH_  64

typedef __attribute__((ext_vector_type(8))) short bf16x8;
typedef __attribute__((ext_vector_type(4))) float f32x4;

static __device__ __forceinline__ unsigned short f2bf(float f){
  unsigned u = __float_as_uint(f);
  u = u + 0x7fffu + ((u >> 16) & 1u);     // RNE
  return (unsigned short)(u >> 16);
}
static __device__ __forceinline__ float bf2f(unsigned short s){
  return __uint_as_float(((unsigned)s) << 16);
}
static __device__ __forceinline__ f32x4 MFMA(bf16x8 a, bf16x8 b, f32x4 c){
  return __builtin_amdgcn_mfma_f32_16x16x32_bf16(a, b, c, 0, 0, 0);
}

union V16 { uint4 u; bf16x8 b; unsigned short s[8]; };

// ---------------- elementwise: fp32 -> bf16 hi/lo split ----------------
__global__ __launch_bounds__(256) void split2_k(const float* __restrict__ src,
                                                unsigned short* __restrict__ hi,
                                                unsigned short* __restrict__ lo, int n4){
  int i = blockIdx.x * 256 + threadIdx.x;
  if (i >= n4) return;
  float4 v = ((const float4*)src)[i];
  ushort4 h, l;
  h.x = f2bf(v.x); l.x = f2bf(v.x - bf2f(h.x));
  h.y = f2bf(v.y); l.y = f2bf(v.y - bf2f(h.y));
  h.z = f2bf(v.z); l.z = f2bf(v.z - bf2f(h.z));
  h.w = f2bf(v.w); l.w = f2bf(v.w - bf2f(h.w));
  ((ushort4*)hi)[i] = h;
  ((ushort4*)lo)[i] = l;
}

// ---------------- elementwise: fp32 -> bf16 ----------------
__global__ __launch_bounds__(256) void cvt_k(const float* __restrict__ src,
                                             unsigned short* __restrict__ dst, int n4){
  int i = blockIdx.x * 256 + threadIdx.x;
  if (i >= n4) return;
  float4 v = ((const float4*)src)[i];
  ushort4 h;
  h.x = f2bf(v.x); h.y = f2bf(v.y); h.z = f2bf(v.z); h.w = f2bf(v.w);
  ((ushort4*)dst)[i] = h;
}

// ---------------- GEMM: C[M,512] = A[M,512] @ W[512,512]^T + bias ----------------
// SPLIT: 3-term hi/lo MFMA for ~fp32 accuracy.
// MODE 0: write fp32 to outF[m*512+n]            (dense output)
// MODE 1: write bf16 hi/lo to [B,H,S,64] arrays  (Q,K heads)
// MODE 2: write bf16 to Vt [B,H,64,S]            (V transposed)
template<bool SPLIT, int MODE>
__global__ __launch_bounds__(256) void gemm_k(
    const unsigned short* __restrict__ Ah, const unsigned short* __restrict__ Al,
    const unsigned short* __restrict__ Bh, const unsigned short* __restrict__ Bl,
    const float* __restrict__ bias,
    float* __restrict__ outF,
    unsigned short* __restrict__ outH, unsigned short* __restrict__ outL)
{
  __shared__ unsigned short lds[(SPLIT ? 4 : 2) * 4096]; // tiles of [128][32] bf16
  const int tid  = threadIdx.x;
  const int lane = tid & 63, w = tid >> 6;
  const int wr = w >> 1, wc = w & 1;
  const int m0 = blockIdx.x * 128, n0 = blockIdx.y * 128;

  f32x4 zero = {0.f, 0.f, 0.f, 0.f};
  f32x4 acc[4][4];
  #pragma unroll
  for (int i = 0; i < 4; i++)
    #pragma unroll
    for (int j = 0; j < 4; j++) acc[i][j] = zero;

  const unsigned short* srcs[4] = {Ah, Bh, Al, Bl};
  const int rb[4] = {m0, n0, m0, n0};

  const int arow = wr * 64 + (lane & 15);
  const int koff = (lane >> 4) * 8;

  for (int kt = 0; kt < 16; kt++){
    uint4 tmp[8];
    #pragma unroll
    for (int t = 0; t < (SPLIT ? 4 : 2); t++){
      #pragma unroll
      for (int p = 0; p < 2; p++){
        int o = (p * 256 + tid) * 16;       // byte offset inside tile
        int r = o >> 6, cb = (o & 63) >> 1; // row, element-in-row
        tmp[t*2+p] = *(const uint4*)(srcs[t] + (size_t)(rb[t] + r) * 512 + kt * 32 + cb);
      }
    }
    __syncthreads();    // previous compute done before overwriting LDS
    #pragma unroll
    for (int t = 0; t < (SPLIT ? 4 : 2); t++){
      #pragma unroll
      for (int p = 0; p < 2; p++){
        int o = (p * 256 + tid) * 16;
        *(uint4*)((char*)(lds + t * 4096) + o) = tmp[t*2+p];
      }
    }
    __syncthreads();

    bf16x8 ah[4], al[4];
    #pragma unroll
    for (int i = 0; i < 4; i++){
      ah[i] = *(const bf16x8*)(lds + 0*4096 + (arow + i*16) * 32 + koff);
      if (SPLIT) al[i] = *(const bf16x8*)(lds + 2*4096 + (arow + i*16) * 32 + koff);
    }
    #pragma unroll
    for (int j = 0; j < 4; j++){
      int brow = wc * 64 + j * 16 + (lane & 15);
      bf16x8 bh = *(const bf16x8*)(lds + 1*4096 + brow * 32 + koff);
      bf16x8 bl;
      if (SPLIT) bl = *(const bf16x8*)(lds + 3*4096 + brow * 32 + koff);
      #pragma unroll
      for (int i = 0; i < 4; i++){
        acc[i][j] = MFMA(ah[i], bh, acc[i][j]);
        if (SPLIT){
          acc[i][j] = MFMA(ah[i], bl, acc[i][j]);
          acc[i][j] = MFMA(al[i], bh, acc[i][j]);
        }
      }
    }
  }

  // epilogue
  #pragma unroll
  for (int j = 0; j < 4; j++){
    int n = n0 + wc * 64 + j * 16 + (lane & 15);
    float bv = bias[n];
    #pragma unroll
    for (int i = 0; i < 4; i++){
      #pragma unroll
      for (int r = 0; r < 4; r++){
        int m = m0 + wr * 64 + i * 16 + (lane >> 4) * 4 + r;
        float c = acc[i][j][r] + bv;
        if (MODE == 0){
          outF[(size_t)m * 512 + n] = c;
        } else if (MODE == 1){
          int bb = m >> 10, s = m & 1023, h = n >> 6, d = n & 63;
          size_t idx = (((size_t)(bb * 8 + h)) * 1024 + s) * 64 + d;
          unsigned short hb = f2bf(c);
          outH[idx] = hb;
          outL[idx] = f2bf(c - bf2f(hb));
        } else {
          int bb = m >> 10, s = m & 1023, h = n >> 6, d = n & 63;
          size_t idx = (((size_t)(bb * 8 + h)) * 64 + d) * 1024 + s;
          outH[idx] = f2bf(c);
        }
      }
    }
  }
}

// ---------------- fused attention core ----------------
// one block = (b, h, 16 q-rows); logits kept in 64KB LDS
__global__ __launch_bounds__(256) void attn_k(
  const unsigned short* __restrict__ qh_h, const unsigned short* __restrict__ qh_l,
  const unsigned short* __restrict__ kh_h, const unsigned short* __restrict__ kh_l,
  const unsigned short* __restrict__ vt,
  const float* __restrict__ dist, const int* __restrict__ mask, const float* __restrict__ adj,
  float* __restrict__ w_out, unsigned short* __restrict__ attnout)
{
  __shared__ float lg[16 * 1024];   // exactly 64 KB
  const int tid = threadIdx.x, lane = tid & 63, w = tid >> 6;

  // swizzle: the 8 heads of one (b,qblk) land on one XCD consecutively
  int p = blockIdx.x;
  int x = p & 7, slot = p >> 3;
  int h = slot & 7, gd8 = slot >> 3;
  int g = gd8 * 8 + x;
  int b = g >> 6, qblk = g & 63;
  int qbase = qblk * 16;
  size_t ho = ((size_t)(b * 8 + h)) << 16;   // *S*DH

  const int koff = (lane >> 4) * 8;

  // ---- phase 1: logits = qh @ kh^T (split bf16, 3 terms) ----
  V16 a00, a01, a10, a11;
  {
    size_t rq = ho + (size_t)(qbase + (lane & 15)) * 64;
    a00.u = *(const uint4*)(qh_h + rq + koff);
    a01.u = *(const uint4*)(qh_h + rq + 32 + koff);
    a10.u = *(const uint4*)(qh_l + rq + koff);
    a11.u = *(const uint4*)(qh_l + rq + 32 + koff);
  }
  for (int ct = 0; ct < 16; ct++){
    int c = w * 16 + ct;
    size_t rk = ho + (size_t)(c * 16 + (lane & 15)) * 64;
    V16 b00, b01, b10, b11;
    b00.u = *(const uint4*)(kh_h + rk + koff);
    b01.u = *(const uint4*)(kh_h + rk + 32 + koff);
    b10.u = *(const uint4*)(kh_l + rk + koff);
    b11.u = *(const uint4*)(kh_l + rk + 32 + koff);
    f32x4 acc = {0.f, 0.f, 0.f, 0.f};
    acc = MFMA(a00.b, b00.b, acc);
    acc = MFMA(a01.b, b01.b, acc);
    acc = MFMA(a00.b, b10.b, acc);
    acc = MFMA(a01.b, b11.b, acc);
    acc = MFMA(a10.b, b00.b, acc);
    acc = MFMA(a11.b, b01.b, acc);
    #pragma unroll
    for (int r = 0; r < 4; r++)
      lg[((lane >> 4) * 4 + r) * 1024 + c * 16 + (lane & 15)] = acc[r];
  }
  __syncthreads();

  // ---- phase 2: relu * rescale(dist)/8 + mask*(-1e9) + adjoin ----
  {
    size_t ebase = (((size_t)b * 1024) + qbase) * 1024;
    #pragma unroll 4
    for (int j = 0; j < 64; j++){
      int e = j * 256 + tid;           // == row*1024 + col
      size_t gi = ebase + (size_t)e;
      float l = lg[e];
      float dd = dist[gi];
      float rs = 3.718281828459045f / (1.f + __expf(1.f - dd));
      l = fmaxf(l, 0.f) * rs * 0.125f;
      l += (float)mask[gi] * (-1e9f);
      l += adj[gi];
      lg[e] = l;
    }
  }
  __syncthreads();

  // ---- phase 3/4: softmax per row + write weights ----
  size_t wrow0 = ((size_t)(b * 8 + h)) * 1024 + qbase;
  #pragma unroll
  for (int rr = 0; rr < 4; rr++){
    int row = w * 4 + rr;
    float* R = lg + row * 1024;
    float m = -3.0e38f;
    #pragma unroll
    for (int i = 0; i < 16; i++) m = fmaxf(m, R[lane + 64 * i]);
    #pragma unroll
    for (int off = 32; off; off >>= 1) m = fmaxf(m, __shfl_xor(m, off));
    float sum = 0.f;
    float ev[16];
    #pragma unroll
    for (int i = 0; i < 16; i++){
      float e = __expf(R[lane + 64 * i] - m);
      ev[i] = e; sum += e;
    }
    #pragma unroll
    for (int off = 32; off; off >>= 1) sum += __shfl_xor(sum, off);
    float inv = 1.f / sum;
    float* WO = w_out + (wrow0 + row) * 1024;
    #pragma unroll
    for (int i = 0; i < 16; i++){
      float wv = ev[i] * inv;
      R[lane + 64 * i] = wv;
      WO[lane + 64 * i] = wv;
    }
  }
  __syncthreads();

  // ---- phase 5: out = P @ V  (wave w owns d-cols w*16..w*16+15) ----
  f32x4 acc = {0.f, 0.f, 0.f, 0.f};
  const unsigned short* V = vt + ho;  // [64][1024]
  int drow = w * 16 + (lane & 15);
  for (int ks = 0; ks < 32; ks++){
    const float* ap = lg + (lane & 15) * 1024 + ks * 32 + koff;
    float4 f0 = *(const float4*)ap;
    float4 f1 = *(const float4*)(ap + 4);
    V16 af;
    af.s[0] = f2bf(f0.x); af.s[1] = f2bf(f0.y); af.s[2] = f2bf(f0.z); af.s[3] = f2bf(f0.w);
    af.s[4] = f2bf(f1.x); af.s[5] = f2bf(f1.y); af.s[6] = f2bf(f1.z); af.s[7] = f2bf(f1.w);
    V16 bv; bv.u = *(const uint4*)(V + (size_t)drow * 1024 + ks * 32 + koff);
    acc = MFMA(af.b, bv.b, acc);
  }
  #pragma unroll
  for (int r = 0; r < 4; r++){
    size_t m = (size_t)b * 1024 + qbase + (lane >> 4) * 4 + r;
    attnout[m * 512 + h * 64 + drow] = f2bf(acc[r]);
  }
}

// ---------------- host ----------------
extern "C" void kernel_launch(void* const* d_in, const int* in_sizes, int n_in,
                              void* d_out, int out_size, void* d_ws, size_t ws_size,
                              hipStream_t stream)
{
  const float* q    = (const float*)d_in[0];
  const float* k    = (const float*)d_in[1];
  const float* v    = (const float*)d_in[2];
  const int*   mask = (const int*)  d_in[3];
  const float* adj  = (const float*)d_in[4];
  const float* dist = (const float*)d_in[5];
  const float* wq_w = (const float*)d_in[6];
  const float* wq_b = (const float*)d_in[7];
  const float* wk_w = (const float*)d_in[8];
  const float* wk_b = (const float*)d_in[9];
  const float* wv_w = (const float*)d_in[10];
  const float* wv_b = (const float*)d_in[11];
  const float* dw   = (const float*)d_in[12];
  const float* db   = (const float*)d_in[13];

  const size_t NQ = (size_t)B_ * S_ * D_;   // 8,388,608
  const size_t NW = (size_t)D_ * D_;        // 262,144

  char* ws = (char*)d_ws;
  size_t off = 0;
  auto alloc = [&](size_t bytes){
    char* pp = ws + off;
    off += (bytes + 255) & ~(size_t)255;
    return pp;
  };
  unsigned short* q_hi  = (unsigned short*)alloc(NQ * 2);
  unsigned short* q_lo  = (unsigned short*)alloc(NQ * 2);
  unsigned short* k_hi  = (unsigned short*)alloc(NQ * 2);
  unsigned short* k_lo  = (unsigned short*)alloc(NQ * 2);
  unsigned short* v_b   = (unsigned short*)alloc(NQ * 2);
  unsigned short* wqh   = (unsigned short*)alloc(NW * 2);
  unsigned short* wql   = (unsigned short*)alloc(NW * 2);
  unsigned short* wkh   = (unsigned short*)alloc(NW * 2);
  unsigned short* wkl   = (unsigned short*)alloc(NW * 2);
  unsigned short* wvb   = (unsigned short*)alloc(NW * 2);
  unsigned short* dwb   = (unsigned short*)alloc(NW * 2);
  unsigned short* qh_hi = (unsigned short*)alloc(NQ * 2);
  unsigned short* qh_lo = (unsigned short*)alloc(NQ * 2);
  unsigned short* kh_hi = (unsigned short*)alloc(NQ * 2);
  unsigned short* kh_lo = (unsigned short*)alloc(NQ * 2);
  unsigned short* vt    = (unsigned short*)alloc(NQ * 2);
  unsigned short* ao    = (unsigned short*)alloc(NQ * 2);

  float* outF  = (float*)d_out;
  float* w_out = (float*)d_out + NQ;

  const int n4q = (int)(NQ / 4), n4w = (int)(NW / 4);

  split2_k<<<n4q / 256, 256, 0, stream>>>(q, q_hi, q_lo, n4q);
  split2_k<<<n4q / 256, 256, 0, stream>>>(k, k_hi, k_lo, n4q);
  split2_k<<<n4w / 256, 256, 0, stream>>>(wq_w, wqh, wql, n4w);
  split2_k<<<n4w / 256, 256, 0, stream>>>(wk_w, wkh, wkl, n4w);
  cvt_k  <<<n4q / 256, 256, 0, stream>>>(v, v_b, n4q);
  cvt_k  <<<n4w / 256, 256, 0, stream>>>(wv_w, wvb, n4w);
  cvt_k  <<<n4w / 256, 256, 0, stream>>>(dw, dwb, n4w);

  dim3 gg(128, 4);
  gemm_k<true, 1><<<gg, 256, 0, stream>>>(q_hi, q_lo, wqh, wql, wq_b, nullptr, qh_hi, qh_lo);
  gemm_k<true, 1><<<gg, 256, 0, stream>>>(k_hi, k_lo, wkh, wkl, wk_b, nullptr, kh_hi, kh_lo);
  gemm_k<false, 2><<<gg, 256, 0, stream>>>(v_b, nullptr, wvb, nullptr, wv_b, nullptr, vt, nullptr);

  attn_k<<<8192, 256, 0, stream>>>(qh_hi, qh_lo, kh_hi, kh_lo, vt,
                                   dist, mask, adj, w_out, ao);

  gemm_k<false, 0><<<gg, 256, 0, stream>>>(ao, nullptr, dwb, nullptr, db, outF, nullptr, nullptr);
}